// Round 3
// baseline (2690534.766 us; speedup 1.0000x reference)
//
#include <hip/hip_runtime.h>

// LSTM decoder, MI355X. Persistent recurrence, round 8.
// r7 post-mortem: flag fabric is fast (burn waves exited instantly); the
// ~17us/step was phase-4's L2-bypassing h-loads (~32K line-reqs/XCD/step,
// 64B-used-per-128B-line). This round: r7's store-only flag fabric + r5's
// per-XCD staged datapath, with all request amplifiers removed:
//  - blocked hbf layout [par][bk][64][8]: 1KB contiguous publish per block,
//    zero false sharing, full-line coherent stores
//  - staging pull fully coalesced: 1024 line-reqs/XCD/step (32x fewer),
//    consumed via plain L2-hit loads after an L1-only buffer_inv sc0
//  - per-XCD join store-only (own xfl word + parallel 16-lane poll)
//  - blocked actb layout: phase-2 full-line coalesced
// L=128, B=64, IN_F=ACT_F=512, H=1024.

#define LSTEPS 128
#define B 64
#define ACTF 512
#define H 1024
#define NB 128             // persistent blocks, co-resident (1/CU at ~104KB LDS)
#define HC 8               // h-columns per block
#define GSTR 33            // LDS gate tile leading-dim pad

typedef short s16x8 __attribute__((ext_vector_type(8)));   // 8 x bf16
typedef short s16x4 __attribute__((ext_vector_type(4)));   // 4 x bf16
typedef float f32x4 __attribute__((ext_vector_type(4)));
typedef unsigned short u16;
typedef unsigned long long u64;

__device__ __forceinline__ u16 f2bf(float f) {
  return __builtin_bit_cast(u16, (__bf16)f);   // RNE
}
__device__ __forceinline__ float sigm(float x) { return 1.f / (1.f + __expf(-x)); }
__device__ __forceinline__ float tanh_fast(float x) { return 2.f / (1.f + __expf(-2.f * x)) - 1.f; }

// cross-XCD coherent (LLC-level) accessors
__device__ __forceinline__ void st8_coh(void* p, u64 v) {
  asm volatile("global_store_dwordx2 %0, %1, off sc0 sc1" :: "v"(p), "v"(v) : "memory");
}
__device__ __forceinline__ void st4_coh(void* p, unsigned v) {
  asm volatile("global_store_dword %0, %1, off sc0 sc1" :: "v"(p), "v"(v) : "memory");
}
__device__ __forceinline__ u64 ld8_coh(const void* p) {
  u64 v;
  asm volatile("global_load_dwordx2 %0, %1, off sc0 sc1\n\ts_waitcnt vmcnt(0)"
               : "=v"(v) : "v"(p) : "memory");
  return v;
}
__device__ __forceinline__ s16x8 ld16_coh(const void* p) {   // issue-only, wait separately
  s16x8 v;
  asm volatile("global_load_dwordx4 %0, %1, off sc0 sc1" : "=v"(v) : "v"(p) : "memory");
  return v;
}
// same-XCD (L2-level) accessors for the staging join
__device__ __forceinline__ void st4_l2(void* p, unsigned v) {
  asm volatile("global_store_dword %0, %1, off sc0" :: "v"(p), "v"(v) : "memory");
}
__device__ __forceinline__ unsigned ld4_l2(const void* p) {
  unsigned v;
  asm volatile("global_load_dword %0, %1, off sc0\n\ts_waitcnt vmcnt(0)"
               : "=v"(v) : "v"(p) : "memory");
  return v;
}

// ---- merged setup kernel: role by block range ----
__global__ void k_setup(const float* __restrict__ act, u16* __restrict__ actb,
                        const float* __restrict__ Wih, const float* __restrict__ Whh,
                        u16* __restrict__ wg,
                        const float* __restrict__ h0, u16* __restrict__ hbf,
                        unsigned* __restrict__ gfl, unsigned* __restrict__ xfl,
                        unsigned* __restrict__ xctr,
                        const float* __restrict__ inf, const float* __restrict__ bih,
                        const float* __restrict__ bhh, float* __restrict__ pre0) {
  const int bb = blockIdx.x;
  const int tid = threadIdx.x;
  if (bb < 2048) {                                   // act fp32 -> bf16, BLOCKED layout
    int id = bb * 256 + tid;                         // 8 contiguous src elems
    const float4* s = (const float4*)act + (size_t)id * 2;
    float4 a = s[0], b = s[1];
    s16x8 o;
    o[0] = (short)f2bf(a.x); o[1] = (short)f2bf(a.y); o[2] = (short)f2bf(a.z); o[3] = (short)f2bf(a.w);
    o[4] = (short)f2bf(b.x); o[5] = (short)f2bf(b.y); o[6] = (short)f2bf(b.z); o[7] = (short)f2bf(b.w);
    // src id = t*4096 + m*64 + chunk  (t=step, m=row, chunk=col/8)
    int t = id >> 12, m = (id >> 6) & 63, ch = id & 63;
    ((s16x8*)actb)[t * 4096 + ch * 64 + m] = o;      // [t][chunk][m][8]
  } else if (bb < 5120) {                            // W fragments (B-frag contiguous)
    int idx = (bb - 2048) * 256 + tid;
    int bk = idx / 6144;
    int lin = idx - bk * 6144;
    int kt = lin >> 7, T = (lin >> 6) & 1, lane = lin & 63;
    int q = lane >> 4, r = lane & 15;
    int local = T * 16 + r;
    int j = (local >> 3) * 1024 + bk * 8 + (local & 7);
    int k = kt * 32 + q * 8;
    const float* src = (k < 512) ? (Wih + (size_t)j * 1024 + 512 + k)
                                 : (Whh + (size_t)j * 1024 + (k - 512));
    s16x8 o;
#pragma unroll
    for (int e = 0; e < 8; ++e) o[e] = (short)f2bf(src[e]);
    ((s16x8*)wg)[(size_t)bk * 6144 + lin] = o;
  } else if (bb < 5152) {                            // h0 -> bf16, BLOCKED, parity 1
    int id = (bb - 5120) * 256 + tid;                // 0..8191, 8 elems each
    const float4* s = (const float4*)h0 + (size_t)id * 2;
    float4 a = s[0], b = s[1];
    s16x8 o;
    o[0] = (short)f2bf(a.x); o[1] = (short)f2bf(a.y); o[2] = (short)f2bf(a.z); o[3] = (short)f2bf(a.w);
    o[4] = (short)f2bf(b.x); o[5] = (short)f2bf(b.y); o[6] = (short)f2bf(b.z); o[7] = (short)f2bf(b.w);
    int row = id >> 7, ch = id & 127;
    ((s16x8*)hbf)[8192 + ch * 64 + row] = o;         // hbf[1][ch][row][8]
    if (bb == 5120) {
      if (tid < 128) gfl[tid] = 0u;
      xfl[tid] = 0u;                                 // 256 words (8 XCD x 32)
      if (tid < 8) xctr[tid] = 0u;
    }
  } else {                                           // PRE0 = IF@Wih[:,:512]^T + b_ih + b_hh
    int o = (bb - 5152) * 256 + tid;
    int bk = o >> 11;
    int rr = o & 2047;
    int b = rr >> 5;
    int local = rr & 31;
    int j = (local >> 3) * 1024 + bk * 8 + (local & 7);
    const float4* xa = (const float4*)(inf + (size_t)b * 512);
    const float4* wa = (const float4*)(Wih + (size_t)j * 1024);
    float s = 0.f;
#pragma unroll 4
    for (int k = 0; k < 128; ++k) {
      float4 x = xa[k], w = wa[k];
      s += x.x * w.x + x.y * w.y + x.z * w.z + x.w * w.w;
    }
    pre0[o] = s + bih[j] + bhh[j];
  }
}

// ---- persistent recurrent kernel ----
__global__ void __launch_bounds__(256, 1) k_rnn(
    const u16* __restrict__ actb, const u16* __restrict__ wg,
    const float* __restrict__ pre0, const float* __restrict__ cinit,
    u16* __restrict__ hbf, u16* __restrict__ stg,
    unsigned* __restrict__ gfl, unsigned* __restrict__ xfl,
    unsigned* __restrict__ xctr, float* __restrict__ out) {
  extern __shared__ char smem[];
  u16* wlds = (u16*)smem;                 // 98304 B: W fragments (persistent)
  float* gl = (float*)(smem + 98304);     // 64 x 33 fp32 gate tile
  __shared__ int s_xcc, s_rank, sdone;

  const int tid = threadIdx.x;
  const int bk = blockIdx.x;
  const int w = tid >> 6;
  const int lane = tid & 63;
  const int q = lane >> 4, r = lane & 15;
  const int n0 = bk * HC;

  // XCD discovery + slice-rank election (empirically 16 blocks/XCD at NB=128)
  if (tid == 0) {
    unsigned xcc;
    asm volatile("s_getreg_b32 %0, hwreg(HW_REG_XCC_ID)" : "=s"(xcc));
    xcc &= 7u;
    s_xcc = (int)xcc;
    s_rank = (int)atomicAdd(&xctr[xcc], 1u);
    sdone = 0;
  }

  {
    const s16x8* src = (const s16x8*)wg + (size_t)bk * 6144;
    s16x8* dst = (s16x8*)wlds;
    for (int i = tid; i < 6144; i += 256) dst[i] = src[i];
  }

  // pointwise ownership: tid<128 -> (row=tid>>1, 4 adjacent cols)
  const int prow = tid >> 1, pcg = (tid & 1) * 4;
  float pr4[16], cr[4];
  if (tid < 128) {
#pragma unroll
    for (int g = 0; g < 4; ++g)
#pragma unroll
      for (int e = 0; e < 4; ++e)
        pr4[g * 4 + e] = pre0[bk * 2048 + prow * 32 + g * 8 + pcg + e];
#pragma unroll
    for (int e = 0; e < 4; ++e) cr[e] = cinit[prow * H + n0 + pcg + e];
  }

  __syncthreads();
  const int xcc = s_xcc;
  const int rk = s_rank;
  u16* stgx = stg + (size_t)xcc * 65536;       // this XCD's staging (u16)
  unsigned* xfx = xfl + xcc * 32;              // this XCD's 16 join words (own line)

  for (int t = 0; t < LSTEPS; ++t) {
    const int par = (t - 1) & 1;               // parity of h(t-1) buffer

    // phase 1: zero gate tile (pre0 is added in the pointwise from registers)
#pragma unroll
    for (int j = 0; j < 8; ++j) {
      int i = j * 256 + tid;
      gl[(i >> 5) * GSTR + (i & 31)] = 0.f;
    }

    f32x4 acc[4][2];
#pragma unroll
    for (int mt = 0; mt < 4; ++mt) {
      f32x4 z = {0.f, 0.f, 0.f, 0.f};
      acc[mt][0] = z; acc[mt][1] = z;
    }

    // phase 2: act-part MFMAs (blocked actb, full-line coalesced) — overlap wait
    const u16* atb = actb + (size_t)t * 32768;
#pragma unroll
    for (int kk = 0; kk < 4; ++kk) {
      const int kt = w * 4 + kk;
      const s16x8* wb = (const s16x8*)wlds + kt * 128;
      s16x8 bf0 = wb[lane];
      s16x8 bf1 = wb[64 + lane];
#pragma unroll
      for (int mt = 0; mt < 4; ++mt) {
        const int m = mt * 16 + r;
        s16x8 af = *(const s16x8*)(atb + kt * 2048 + q * 512 + m * 8);
        acc[mt][0] = __builtin_amdgcn_mfma_f32_16x16x32_bf16(af, bf0, acc[mt][0], 0, 0, 0);
        acc[mt][1] = __builtin_amdgcn_mfma_f32_16x16x32_bf16(af, bf1, acc[mt][1], 0, 0, 0);
      }
    }

    // phase 3a: global join on h(t-1) publication (store-only flags, r7 fabric)
    if (t) {
      if (w == 0) {
        const unsigned* fp = gfl + 2 * lane;
        unsigned g = 0;
        for (;;) {
          u64 v = ld8_coh(fp);
          if ((unsigned)v >= (unsigned)t && (unsigned)(v >> 32) >= (unsigned)t) break;
          if (++g > (1u << 20)) break;   // bounded spin: wrong-answer beats hang
        }
        if (tid == 0) *(volatile int*)&sdone = t;
      } else {
        float b0 = 1.0f + (float)lane * 1e-7f;
        float b1 = 1.0000001f;
        for (;;) {
#pragma unroll
          for (int u = 0; u < 32; ++u)
            asm volatile("v_fmac_f32 %0, %1, %2" : "+v"(b0) : "v"(b1), "v"(b1));
          if (*(volatile int*)&sdone >= t) break;
        }
        asm volatile("" :: "v"(b0));     // keep the burn chain live
      }
    }
    __syncthreads();

    // phase 3b: distributed per-XCD staging pull — slice rk, fully coalesced
    // (8KB contiguous per block thanks to the blocked hbf layout)
    if (rk < 16) {
      const u16* src = hbf + par * 65536 + rk * 4096 + tid * 8;
      u16* dst = stgx + rk * 4096 + tid * 8;
      s16x8 v0 = ld16_coh(src);
      s16x8 v1 = ld16_coh(src + 2048);
      asm volatile("s_waitcnt vmcnt(0)" ::: "memory");
      *(s16x8*)dst = v0;
      *(s16x8*)(dst + 2048) = v1;
      asm volatile("s_waitcnt vmcnt(0)" ::: "memory");
    }
    __syncthreads();
    if (tid == 0 && rk < 16) st4_l2(xfx + rk, (unsigned)(t + 1));
    if (w == 0 && lane < 16) {
      unsigned g = 0;
      while (ld4_l2(xfx + lane) < (unsigned)(t + 1)) {
        if (++g > (1u << 18)) break;
      }
    }
    __syncthreads();
    asm volatile("buffer_inv sc0" ::: "memory");   // L1-only: drop stale staging lines

    // phase 4: h-part MFMAs from own-XCD L2 staging, plain cached loads,
    // full-line coalesced (16 consecutive r-lanes -> 256B contiguous)
#pragma unroll
    for (int kk = 0; kk < 8; ++kk) {
      const int kt16 = w * 8 + kk;
      const s16x8* wb = (const s16x8*)wlds + (16 + kt16) * 128;
      s16x8 bf0 = wb[lane];
      s16x8 bf1 = wb[64 + lane];
#pragma unroll
      for (int mt = 0; mt < 4; ++mt) {
        const int m = mt * 16 + r;
        s16x8 af = *(const s16x8*)(stgx + kt16 * 2048 + q * 512 + m * 8);
        acc[mt][0] = __builtin_amdgcn_mfma_f32_16x16x32_bf16(af, bf0, acc[mt][0], 0, 0, 0);
        acc[mt][1] = __builtin_amdgcn_mfma_f32_16x16x32_bf16(af, bf1, acc[mt][1], 0, 0, 0);
      }
    }

    // phase 5: cross-wave K reduction into gate tile
#pragma unroll
    for (int mt = 0; mt < 4; ++mt) {
      const int bb2 = mt * 16 + q * 4;
#pragma unroll
      for (int T = 0; T < 2; ++T) {
        const int lc = T * 16 + r;
#pragma unroll
        for (int e = 0; e < 4; ++e)
          atomicAdd(&gl[(bb2 + e) * GSTR + lc], acc[mt][T][e]);
      }
    }
    __syncthreads();

    // phase 6: pointwise (tid<128: one row, 4 adjacent cols) + publication.
    // h published in BLOCKED layout: block-exclusive 1KB chunk, full lines.
    if (tid < 128) {
      float hv[4];
#pragma unroll
      for (int e = 0; e < 4; ++e) {
        const int c = pcg + e;
        float ig = sigm(gl[prow * GSTR + c] + pr4[e]);
        float fg = sigm(gl[prow * GSTR + 8 + c] + pr4[4 + e]);
        float gg = tanh_fast(gl[prow * GSTR + 16 + c] + pr4[8 + e]);
        float og = sigm(gl[prow * GSTR + 24 + c] + pr4[12 + e]);
        cr[e] = fg * cr[e] + ig * gg;
        hv[e] = og * tanh_fast(cr[e]);
      }
      if (t < LSTEPS - 1) {
        s16x4 hb; hb[0] = (short)f2bf(hv[0]); hb[1] = (short)f2bf(hv[1]);
        hb[2] = (short)f2bf(hv[2]); hb[3] = (short)f2bf(hv[3]);
        st8_coh(hbf + (t & 1) * 65536 + bk * 512 + prow * 8 + pcg,
                __builtin_bit_cast(u64, hb));
      }
      f32x4 hv4; hv4[0] = hv[0]; hv4[1] = hv[1]; hv4[2] = hv[2]; hv4[3] = hv[3];
      *(f32x4*)(out + (size_t)t * (B * H) + prow * H + n0 + pcg) = hv4;  // plain
      if (t == LSTEPS - 1) {
        float* hn = out + (size_t)LSTEPS * (B * H);
        float* cn = hn + B * H;
        f32x4 cr4; cr4[0] = cr[0]; cr4[1] = cr[1]; cr4[2] = cr[2]; cr4[3] = cr[3];
        *(f32x4*)(hn + prow * H + n0 + pcg) = hv4;
        *(f32x4*)(cn + prow * H + n0 + pcg) = cr4;
      }
    }

    // publish: drain h stores, block-join, set this block's flag (store-only)
    if (t < LSTEPS - 1) {
      asm volatile("s_waitcnt vmcnt(0)" ::: "memory");
      __syncthreads();
      if (tid == 0) st4_coh(gfl + bk, (unsigned)(t + 1));
    }
  }
}

extern "C" void kernel_launch(void* const* d_in, const int* in_sizes, int n_in,
                              void* d_out, int out_size, void* d_ws, size_t ws_size,
                              hipStream_t stream) {
  const float* inf = (const float*)d_in[0];
  const float* act = (const float*)d_in[1];
  const float* h0  = (const float*)d_in[2];
  const float* cst = (const float*)d_in[3];
  const float* Wih = (const float*)d_in[4];
  const float* Whh = (const float*)d_in[5];
  const float* bih = (const float*)d_in[6];
  const float* bhh = (const float*)d_in[7];
  float* out = (float*)d_out;

  char* ws = (char*)d_ws;
  u16* actb      = (u16*)ws;                    //  8,388,608 B (blocked [t][ch][m][8])
  u16* wg        = (u16*)(ws + 8388608);        // 12,582,912 B
  float* pre0    = (float*)(ws + 20971520);     //  1,048,576 B
  u16* hbf       = (u16*)(ws + 22020096);       //    262,144 B (2 par x 128 blk x 1KB)
  u16* stg       = (u16*)(ws + 22282240);       //  1,048,576 B (8 XCD x 128KB)
  unsigned* gfl  = (unsigned*)(ws + 24379456);  //        512 B (128 per-block flags)
  unsigned* xct  = (unsigned*)(ws + 24379968);  //         32 B (rank election)
  unsigned* xfl  = (unsigned*)(ws + 24380416);  //      1,024 B (8 XCD x 32 words)

  hipLaunchKernelGGL(k_setup, dim3(6176), dim3(256), 0, stream,
                     act, actb, Wih, Whh, wg, h0, hbf, gfl, xfl, xct,
                     inf, bih, bhh, pre0);

  hipFuncSetAttribute((const void*)k_rnn, hipFuncAttributeMaxDynamicSharedMemorySize, 106752);
  hipLaunchKernelGGL(k_rnn, dim3(NB), dim3(256), 106752, stream,
                     actb, wg, pre0, cst, hbf, stg, gfl, xfl, xct, out);
}

// Round 4
// 2557.473 us; speedup vs baseline: 1052.0287x; 1052.0287x over previous
//
#include <hip/hip_runtime.h>

// LSTM decoder, MI355X. Persistent recurrence, round 9.
// r8 post-mortem: datapath fine, but the per-XCD join used sc0-only
// loads/stores -> no CU-to-CU visibility -> bounded spin expired EVERY step
// (21ms/step). Fix: xfl join uses the proven sc0 sc1 LLC-coherent pair
// (identical primitive to the r7 global-join fabric). Everything else kept:
//  - blocked hbf layout [par][bk][64][8]: 1KB contiguous publish per block
//  - staging pull fully coalesced: 1024 line-reqs/XCD/step, consumed via
//    plain L2-hit loads after an L1-only buffer_inv sc0
//  - store-only join fabrics everywhere (no atomic RMW on hot path)
//  - blocked actb layout: phase-2 full-line coalesced
// L=128, B=64, IN_F=ACT_F=512, H=1024.

#define LSTEPS 128
#define B 64
#define ACTF 512
#define H 1024
#define NB 128             // persistent blocks, co-resident (1/CU at ~104KB LDS)
#define HC 8               // h-columns per block
#define GSTR 33            // LDS gate tile leading-dim pad

typedef short s16x8 __attribute__((ext_vector_type(8)));   // 8 x bf16
typedef short s16x4 __attribute__((ext_vector_type(4)));   // 4 x bf16
typedef float f32x4 __attribute__((ext_vector_type(4)));
typedef unsigned short u16;
typedef unsigned long long u64;

__device__ __forceinline__ u16 f2bf(float f) {
  return __builtin_bit_cast(u16, (__bf16)f);   // RNE
}
__device__ __forceinline__ float sigm(float x) { return 1.f / (1.f + __expf(-x)); }
__device__ __forceinline__ float tanh_fast(float x) { return 2.f / (1.f + __expf(-2.f * x)) - 1.f; }

// cross-XCD coherent (LLC-level) accessors — the only visibility primitive
// that has been hardware-validated in this session (r7).
__device__ __forceinline__ void st8_coh(void* p, u64 v) {
  asm volatile("global_store_dwordx2 %0, %1, off sc0 sc1" :: "v"(p), "v"(v) : "memory");
}
__device__ __forceinline__ void st4_coh(void* p, unsigned v) {
  asm volatile("global_store_dword %0, %1, off sc0 sc1" :: "v"(p), "v"(v) : "memory");
}
__device__ __forceinline__ u64 ld8_coh(const void* p) {
  u64 v;
  asm volatile("global_load_dwordx2 %0, %1, off sc0 sc1\n\ts_waitcnt vmcnt(0)"
               : "=v"(v) : "v"(p) : "memory");
  return v;
}
__device__ __forceinline__ unsigned ld4_coh(const void* p) {
  unsigned v;
  asm volatile("global_load_dword %0, %1, off sc0 sc1\n\ts_waitcnt vmcnt(0)"
               : "=v"(v) : "v"(p) : "memory");
  return v;
}
__device__ __forceinline__ s16x8 ld16_coh(const void* p) {   // issue-only, wait separately
  s16x8 v;
  asm volatile("global_load_dwordx4 %0, %1, off sc0 sc1" : "=v"(v) : "v"(p) : "memory");
  return v;
}

// ---- merged setup kernel: role by block range ----
__global__ void k_setup(const float* __restrict__ act, u16* __restrict__ actb,
                        const float* __restrict__ Wih, const float* __restrict__ Whh,
                        u16* __restrict__ wg,
                        const float* __restrict__ h0, u16* __restrict__ hbf,
                        unsigned* __restrict__ gfl, unsigned* __restrict__ xfl,
                        unsigned* __restrict__ xctr,
                        const float* __restrict__ inf, const float* __restrict__ bih,
                        const float* __restrict__ bhh, float* __restrict__ pre0) {
  const int bb = blockIdx.x;
  const int tid = threadIdx.x;
  if (bb < 2048) {                                   // act fp32 -> bf16, BLOCKED layout
    int id = bb * 256 + tid;                         // 8 contiguous src elems
    const float4* s = (const float4*)act + (size_t)id * 2;
    float4 a = s[0], b = s[1];
    s16x8 o;
    o[0] = (short)f2bf(a.x); o[1] = (short)f2bf(a.y); o[2] = (short)f2bf(a.z); o[3] = (short)f2bf(a.w);
    o[4] = (short)f2bf(b.x); o[5] = (short)f2bf(b.y); o[6] = (short)f2bf(b.z); o[7] = (short)f2bf(b.w);
    // src id = t*4096 + m*64 + chunk  (t=step, m=row, chunk=col/8)
    int t = id >> 12, m = (id >> 6) & 63, ch = id & 63;
    ((s16x8*)actb)[t * 4096 + ch * 64 + m] = o;      // [t][chunk][m][8]
  } else if (bb < 5120) {                            // W fragments (B-frag contiguous)
    int idx = (bb - 2048) * 256 + tid;
    int bk = idx / 6144;
    int lin = idx - bk * 6144;
    int kt = lin >> 7, T = (lin >> 6) & 1, lane = lin & 63;
    int q = lane >> 4, r = lane & 15;
    int local = T * 16 + r;
    int j = (local >> 3) * 1024 + bk * 8 + (local & 7);
    int k = kt * 32 + q * 8;
    const float* src = (k < 512) ? (Wih + (size_t)j * 1024 + 512 + k)
                                 : (Whh + (size_t)j * 1024 + (k - 512));
    s16x8 o;
#pragma unroll
    for (int e = 0; e < 8; ++e) o[e] = (short)f2bf(src[e]);
    ((s16x8*)wg)[(size_t)bk * 6144 + lin] = o;
  } else if (bb < 5152) {                            // h0 -> bf16, BLOCKED, parity 1
    int id = (bb - 5120) * 256 + tid;                // 0..8191, 8 elems each
    const float4* s = (const float4*)h0 + (size_t)id * 2;
    float4 a = s[0], b = s[1];
    s16x8 o;
    o[0] = (short)f2bf(a.x); o[1] = (short)f2bf(a.y); o[2] = (short)f2bf(a.z); o[3] = (short)f2bf(a.w);
    o[4] = (short)f2bf(b.x); o[5] = (short)f2bf(b.y); o[6] = (short)f2bf(b.z); o[7] = (short)f2bf(b.w);
    int row = id >> 7, ch = id & 127;
    ((s16x8*)hbf)[8192 + ch * 64 + row] = o;         // hbf[1][ch][row][8]
    if (bb == 5120) {
      if (tid < 128) gfl[tid] = 0u;
      xfl[tid] = 0u;                                 // 256 words (8 XCD x 32)
      if (tid < 8) xctr[tid] = 0u;
    }
  } else {                                           // PRE0 = IF@Wih[:,:512]^T + b_ih + b_hh
    int o = (bb - 5152) * 256 + tid;
    int bk = o >> 11;
    int rr = o & 2047;
    int b = rr >> 5;
    int local = rr & 31;
    int j = (local >> 3) * 1024 + bk * 8 + (local & 7);
    const float4* xa = (const float4*)(inf + (size_t)b * 512);
    const float4* wa = (const float4*)(Wih + (size_t)j * 1024);
    float s = 0.f;
#pragma unroll 4
    for (int k = 0; k < 128; ++k) {
      float4 x = xa[k], w = wa[k];
      s += x.x * w.x + x.y * w.y + x.z * w.z + x.w * w.w;
    }
    pre0[o] = s + bih[j] + bhh[j];
  }
}

// ---- persistent recurrent kernel ----
__global__ void __launch_bounds__(256, 1) k_rnn(
    const u16* __restrict__ actb, const u16* __restrict__ wg,
    const float* __restrict__ pre0, const float* __restrict__ cinit,
    u16* __restrict__ hbf, u16* __restrict__ stg,
    unsigned* __restrict__ gfl, unsigned* __restrict__ xfl,
    unsigned* __restrict__ xctr, float* __restrict__ out) {
  extern __shared__ char smem[];
  u16* wlds = (u16*)smem;                 // 98304 B: W fragments (persistent)
  float* gl = (float*)(smem + 98304);     // 64 x 33 fp32 gate tile
  __shared__ int s_xcc, s_rank, sdone;

  const int tid = threadIdx.x;
  const int bk = blockIdx.x;
  const int w = tid >> 6;
  const int lane = tid & 63;
  const int q = lane >> 4, r = lane & 15;
  const int n0 = bk * HC;

  // XCD discovery + slice-rank election (validated 16 blocks/XCD by r5 timing)
  if (tid == 0) {
    unsigned xcc;
    asm volatile("s_getreg_b32 %0, hwreg(HW_REG_XCC_ID)" : "=s"(xcc));
    xcc &= 7u;
    s_xcc = (int)xcc;
    s_rank = (int)atomicAdd(&xctr[xcc], 1u);
    sdone = 0;
  }

  {
    const s16x8* src = (const s16x8*)wg + (size_t)bk * 6144;
    s16x8* dst = (s16x8*)wlds;
    for (int i = tid; i < 6144; i += 256) dst[i] = src[i];
  }

  // pointwise ownership: tid<128 -> (row=tid>>1, 4 adjacent cols)
  const int prow = tid >> 1, pcg = (tid & 1) * 4;
  float pr4[16], cr[4];
  if (tid < 128) {
#pragma unroll
    for (int g = 0; g < 4; ++g)
#pragma unroll
      for (int e = 0; e < 4; ++e)
        pr4[g * 4 + e] = pre0[bk * 2048 + prow * 32 + g * 8 + pcg + e];
#pragma unroll
    for (int e = 0; e < 4; ++e) cr[e] = cinit[prow * H + n0 + pcg + e];
  }

  __syncthreads();
  const int xcc = s_xcc;
  const int rk = s_rank;
  u16* stgx = stg + (size_t)xcc * 65536;       // this XCD's staging (u16)
  unsigned* xfx = xfl + xcc * 32;              // this XCD's 16 join words (own line)

  for (int t = 0; t < LSTEPS; ++t) {
    const int par = (t - 1) & 1;               // parity of h(t-1) buffer

    // phase 1: zero gate tile (pre0 is added in the pointwise from registers)
#pragma unroll
    for (int j = 0; j < 8; ++j) {
      int i = j * 256 + tid;
      gl[(i >> 5) * GSTR + (i & 31)] = 0.f;
    }

    f32x4 acc[4][2];
#pragma unroll
    for (int mt = 0; mt < 4; ++mt) {
      f32x4 z = {0.f, 0.f, 0.f, 0.f};
      acc[mt][0] = z; acc[mt][1] = z;
    }

    // phase 2: act-part MFMAs (blocked actb, full-line coalesced) — overlap wait
    const u16* atb = actb + (size_t)t * 32768;
#pragma unroll
    for (int kk = 0; kk < 4; ++kk) {
      const int kt = w * 4 + kk;
      const s16x8* wb = (const s16x8*)wlds + kt * 128;
      s16x8 bf0 = wb[lane];
      s16x8 bf1 = wb[64 + lane];
#pragma unroll
      for (int mt = 0; mt < 4; ++mt) {
        const int m = mt * 16 + r;
        s16x8 af = *(const s16x8*)(atb + kt * 2048 + q * 512 + m * 8);
        acc[mt][0] = __builtin_amdgcn_mfma_f32_16x16x32_bf16(af, bf0, acc[mt][0], 0, 0, 0);
        acc[mt][1] = __builtin_amdgcn_mfma_f32_16x16x32_bf16(af, bf1, acc[mt][1], 0, 0, 0);
      }
    }

    // phase 3a: global join on h(t-1) publication (store-only flags, r7 fabric)
    if (t) {
      if (w == 0) {
        const unsigned* fp = gfl + 2 * lane;
        unsigned g = 0;
        for (;;) {
          u64 v = ld8_coh(fp);
          if ((unsigned)v >= (unsigned)t && (unsigned)(v >> 32) >= (unsigned)t) break;
          if (++g > (1u << 20)) break;   // bounded spin: wrong-answer beats hang
        }
        if (tid == 0) *(volatile int*)&sdone = t;
      } else {
        float b0 = 1.0f + (float)lane * 1e-7f;
        float b1 = 1.0000001f;
        for (;;) {
#pragma unroll
          for (int u = 0; u < 32; ++u)
            asm volatile("v_fmac_f32 %0, %1, %2" : "+v"(b0) : "v"(b1), "v"(b1));
          if (*(volatile int*)&sdone >= t) break;
        }
        asm volatile("" :: "v"(b0));     // keep the burn chain live
      }
    }
    __syncthreads();

    // phase 3b: distributed per-XCD staging pull — slice rk, fully coalesced
    // (8KB contiguous per block thanks to the blocked hbf layout)
    if (rk < 16) {
      const u16* src = hbf + par * 65536 + rk * 4096 + tid * 8;
      u16* dst = stgx + rk * 4096 + tid * 8;
      s16x8 v0 = ld16_coh(src);
      s16x8 v1 = ld16_coh(src + 2048);
      asm volatile("s_waitcnt vmcnt(0)" ::: "memory");
      *(s16x8*)dst = v0;                         // plain: land in own-XCD L2
      *(s16x8*)(dst + 2048) = v1;
      asm volatile("s_waitcnt vmcnt(0)" ::: "memory");
    }
    __syncthreads();
    // per-XCD join: sc0 sc1 store + sc0 sc1 poll (FIX vs r8's sc0-only).
    if (tid == 0 && rk < 16) st4_coh(xfx + rk, (unsigned)(t + 1));
    if (w == 0 && lane < 16) {
      unsigned g = 0;
      while (ld4_coh(xfx + lane) < (unsigned)(t + 1)) {
        if (++g > (1u << 16)) break;   // bounded spin, cheap failure mode
      }
    }
    __syncthreads();
    asm volatile("buffer_inv sc0" ::: "memory");   // L1-only: drop stale staging lines

    // phase 4: h-part MFMAs from own-XCD L2 staging, plain cached loads,
    // full-line coalesced (16 consecutive r-lanes -> 256B contiguous)
#pragma unroll
    for (int kk = 0; kk < 8; ++kk) {
      const int kt16 = w * 8 + kk;
      const s16x8* wb = (const s16x8*)wlds + (16 + kt16) * 128;
      s16x8 bf0 = wb[lane];
      s16x8 bf1 = wb[64 + lane];
#pragma unroll
      for (int mt = 0; mt < 4; ++mt) {
        const int m = mt * 16 + r;
        s16x8 af = *(const s16x8*)(stgx + kt16 * 2048 + q * 512 + m * 8);
        acc[mt][0] = __builtin_amdgcn_mfma_f32_16x16x32_bf16(af, bf0, acc[mt][0], 0, 0, 0);
        acc[mt][1] = __builtin_amdgcn_mfma_f32_16x16x32_bf16(af, bf1, acc[mt][1], 0, 0, 0);
      }
    }

    // phase 5: cross-wave K reduction into gate tile
#pragma unroll
    for (int mt = 0; mt < 4; ++mt) {
      const int bb2 = mt * 16 + q * 4;
#pragma unroll
      for (int T = 0; T < 2; ++T) {
        const int lc = T * 16 + r;
#pragma unroll
        for (int e = 0; e < 4; ++e)
          atomicAdd(&gl[(bb2 + e) * GSTR + lc], acc[mt][T][e]);
      }
    }
    __syncthreads();

    // phase 6: pointwise (tid<128: one row, 4 adjacent cols) + publication.
    // h published in BLOCKED layout: block-exclusive 1KB chunk, full lines.
    if (tid < 128) {
      float hv[4];
#pragma unroll
      for (int e = 0; e < 4; ++e) {
        const int c = pcg + e;
        float ig = sigm(gl[prow * GSTR + c] + pr4[e]);
        float fg = sigm(gl[prow * GSTR + 8 + c] + pr4[4 + e]);
        float gg = tanh_fast(gl[prow * GSTR + 16 + c] + pr4[8 + e]);
        float og = sigm(gl[prow * GSTR + 24 + c] + pr4[12 + e]);
        cr[e] = fg * cr[e] + ig * gg;
        hv[e] = og * tanh_fast(cr[e]);
      }
      if (t < LSTEPS - 1) {
        s16x4 hb; hb[0] = (short)f2bf(hv[0]); hb[1] = (short)f2bf(hv[1]);
        hb[2] = (short)f2bf(hv[2]); hb[3] = (short)f2bf(hv[3]);
        st8_coh(hbf + (t & 1) * 65536 + bk * 512 + prow * 8 + pcg,
                __builtin_bit_cast(u64, hb));
      }
      f32x4 hv4; hv4[0] = hv[0]; hv4[1] = hv[1]; hv4[2] = hv[2]; hv4[3] = hv[3];
      *(f32x4*)(out + (size_t)t * (B * H) + prow * H + n0 + pcg) = hv4;  // plain
      if (t == LSTEPS - 1) {
        float* hn = out + (size_t)LSTEPS * (B * H);
        float* cn = hn + B * H;
        f32x4 cr4; cr4[0] = cr[0]; cr4[1] = cr[1]; cr4[2] = cr[2]; cr4[3] = cr[3];
        *(f32x4*)(hn + prow * H + n0 + pcg) = hv4;
        *(f32x4*)(cn + prow * H + n0 + pcg) = cr4;
      }
    }

    // publish: drain h stores, block-join, set this block's flag (store-only)
    if (t < LSTEPS - 1) {
      asm volatile("s_waitcnt vmcnt(0)" ::: "memory");
      __syncthreads();
      if (tid == 0) st4_coh(gfl + bk, (unsigned)(t + 1));
    }
  }
}

extern "C" void kernel_launch(void* const* d_in, const int* in_sizes, int n_in,
                              void* d_out, int out_size, void* d_ws, size_t ws_size,
                              hipStream_t stream) {
  const float* inf = (const float*)d_in[0];
  const float* act = (const float*)d_in[1];
  const float* h0  = (const float*)d_in[2];
  const float* cst = (const float*)d_in[3];
  const float* Wih = (const float*)d_in[4];
  const float* Whh = (const float*)d_in[5];
  const float* bih = (const float*)d_in[6];
  const float* bhh = (const float*)d_in[7];
  float* out = (float*)d_out;

  char* ws = (char*)d_ws;
  u16* actb      = (u16*)ws;                    //  8,388,608 B (blocked [t][ch][m][8])
  u16* wg        = (u16*)(ws + 8388608);        // 12,582,912 B
  float* pre0    = (float*)(ws + 20971520);     //  1,048,576 B
  u16* hbf       = (u16*)(ws + 22020096);       //    262,144 B (2 par x 128 blk x 1KB)
  u16* stg       = (u16*)(ws + 22282240);       //  1,048,576 B (8 XCD x 128KB)
  unsigned* gfl  = (unsigned*)(ws + 24379456);  //        512 B (128 per-block flags)
  unsigned* xct  = (unsigned*)(ws + 24379968);  //         32 B (rank election)
  unsigned* xfl  = (unsigned*)(ws + 24380416);  //      1,024 B (8 XCD x 32 words)

  hipLaunchKernelGGL(k_setup, dim3(6176), dim3(256), 0, stream,
                     act, actb, Wih, Whh, wg, h0, hbf, gfl, xfl, xct,
                     inf, bih, bhh, pre0);

  hipFuncSetAttribute((const void*)k_rnn, hipFuncAttributeMaxDynamicSharedMemorySize, 106752);
  hipLaunchKernelGGL(k_rnn, dim3(NB), dim3(256), 106752, stream,
                     actb, wg, pre0, cst, hbf, stg, gfl, xfl, xct, out);
}

// Round 5
// 2158.689 us; speedup vs baseline: 1246.3744x; 1.1847x over previous
//
#include <hip/hip_runtime.h>

// LSTM decoder, MI355X. Persistent recurrence, round 10.
// r9 post-mortem: three different sync fabrics all land ~18us/step -> the
// cost is the per-step SERIAL PHASE CHAIN, not the join primitive. This
// round removes chain links instead of swapping them:
//  - NO global join, NO per-XCD join, NO staging bounce, NO buffer_inv,
//    NO burn waves. Wave w only consumes k-tiles w*8..w*8+7 = producers
//    w*32..w*32+31, so lanes 0-31 of each wave poll exactly those 32 flags
//    (overlapped with the act-GEMM) and proceed independently.
//  - h(t-1) read DIRECTLY from the blocked hbf with coherent 16B loads,
//    fully coalesced (full 128B lines), register-double-buffered into MFMAs
//    (vmcnt(4) pipeline), exactly the proven r7 structure + r9 layout.
//  - publish: h-store (sc0sc1) issued before out-store, drained with
//    vmcnt(1) (in-order retirement -> h done, out may linger), barrier,
//    store-only flag. One LLC visibility hop per step.
//  - parity-buffer safety: flag=t+1 is set after ALL 4 waves of a block
//    passed the phase-5 barrier (hence finished reading h(t-1)); a writer
//    of h(t+1) has collectively polled all 128 flags >= t+1 across its 4
//    waves before phase 6. Full join is implicit at the phase-5 barrier.
// L=128, B=64, IN_F=ACT_F=512, H=1024.

#define LSTEPS 128
#define B 64
#define ACTF 512
#define H 1024
#define NB 128             // persistent blocks, co-resident (1/CU at ~104KB LDS)
#define HC 8               // h-columns per block
#define GSTR 33            // LDS gate tile leading-dim pad

typedef short s16x8 __attribute__((ext_vector_type(8)));   // 8 x bf16
typedef short s16x4 __attribute__((ext_vector_type(4)));   // 4 x bf16
typedef float f32x4 __attribute__((ext_vector_type(4)));
typedef unsigned short u16;
typedef unsigned long long u64;

__device__ __forceinline__ u16 f2bf(float f) {
  return __builtin_bit_cast(u16, (__bf16)f);   // RNE
}
__device__ __forceinline__ float sigm(float x) { return 1.f / (1.f + __expf(-x)); }
__device__ __forceinline__ float tanh_fast(float x) { return 2.f / (1.f + __expf(-2.f * x)) - 1.f; }

// cross-XCD coherent (LLC-level) accessors — hardware-validated in r7.
__device__ __forceinline__ void st8_coh(void* p, u64 v) {
  asm volatile("global_store_dwordx2 %0, %1, off sc0 sc1" :: "v"(p), "v"(v) : "memory");
}
__device__ __forceinline__ void st4_coh(void* p, unsigned v) {
  asm volatile("global_store_dword %0, %1, off sc0 sc1" :: "v"(p), "v"(v) : "memory");
}
__device__ __forceinline__ unsigned ld4_coh(const void* p) {
  unsigned v;
  asm volatile("global_load_dword %0, %1, off sc0 sc1\n\ts_waitcnt vmcnt(0)"
               : "=v"(v) : "v"(p) : "memory");
  return v;
}

// ---- merged setup kernel: role by block range (unchanged from r9) ----
__global__ void k_setup(const float* __restrict__ act, u16* __restrict__ actb,
                        const float* __restrict__ Wih, const float* __restrict__ Whh,
                        u16* __restrict__ wg,
                        const float* __restrict__ h0, u16* __restrict__ hbf,
                        unsigned* __restrict__ gfl,
                        const float* __restrict__ inf, const float* __restrict__ bih,
                        const float* __restrict__ bhh, float* __restrict__ pre0) {
  const int bb = blockIdx.x;
  const int tid = threadIdx.x;
  if (bb < 2048) {                                   // act fp32 -> bf16, BLOCKED layout
    int id = bb * 256 + tid;                         // 8 contiguous src elems
    const float4* s = (const float4*)act + (size_t)id * 2;
    float4 a = s[0], b = s[1];
    s16x8 o;
    o[0] = (short)f2bf(a.x); o[1] = (short)f2bf(a.y); o[2] = (short)f2bf(a.z); o[3] = (short)f2bf(a.w);
    o[4] = (short)f2bf(b.x); o[5] = (short)f2bf(b.y); o[6] = (short)f2bf(b.z); o[7] = (short)f2bf(b.w);
    // src id = t*4096 + m*64 + chunk  (t=step, m=row, chunk=col/8)
    int t = id >> 12, m = (id >> 6) & 63, ch = id & 63;
    ((s16x8*)actb)[t * 4096 + ch * 64 + m] = o;      // [t][chunk][m][8]
  } else if (bb < 5120) {                            // W fragments (B-frag contiguous)
    int idx = (bb - 2048) * 256 + tid;
    int bk = idx / 6144;
    int lin = idx - bk * 6144;
    int kt = lin >> 7, T = (lin >> 6) & 1, lane = lin & 63;
    int q = lane >> 4, r = lane & 15;
    int local = T * 16 + r;
    int j = (local >> 3) * 1024 + bk * 8 + (local & 7);
    int k = kt * 32 + q * 8;
    const float* src = (k < 512) ? (Wih + (size_t)j * 1024 + 512 + k)
                                 : (Whh + (size_t)j * 1024 + (k - 512));
    s16x8 o;
#pragma unroll
    for (int e = 0; e < 8; ++e) o[e] = (short)f2bf(src[e]);
    ((s16x8*)wg)[(size_t)bk * 6144 + lin] = o;
  } else if (bb < 5152) {                            // h0 -> bf16, BLOCKED, parity 1
    int id = (bb - 5120) * 256 + tid;                // 0..8191, 8 elems each
    const float4* s = (const float4*)h0 + (size_t)id * 2;
    float4 a = s[0], b = s[1];
    s16x8 o;
    o[0] = (short)f2bf(a.x); o[1] = (short)f2bf(a.y); o[2] = (short)f2bf(a.z); o[3] = (short)f2bf(a.w);
    o[4] = (short)f2bf(b.x); o[5] = (short)f2bf(b.y); o[6] = (short)f2bf(b.z); o[7] = (short)f2bf(b.w);
    int row = id >> 7, ch = id & 127;
    ((s16x8*)hbf)[8192 + ch * 64 + row] = o;         // hbf[1][ch][row][8]
    if (bb == 5120 && tid < 128) gfl[tid] = 0u;
  } else {                                           // PRE0 = IF@Wih[:,:512]^T + b_ih + b_hh
    int o = (bb - 5152) * 256 + tid;
    int bk = o >> 11;
    int rr = o & 2047;
    int b = rr >> 5;
    int local = rr & 31;
    int j = (local >> 3) * 1024 + bk * 8 + (local & 7);
    const float4* xa = (const float4*)(inf + (size_t)b * 512);
    const float4* wa = (const float4*)(Wih + (size_t)j * 1024);
    float s = 0.f;
#pragma unroll 4
    for (int k = 0; k < 128; ++k) {
      float4 x = xa[k], w = wa[k];
      s += x.x * w.x + x.y * w.y + x.z * w.z + x.w * w.w;
    }
    pre0[o] = s + bih[j] + bhh[j];
  }
}

// ---- persistent recurrent kernel ----
__global__ void __launch_bounds__(256, 1) k_rnn(
    const u16* __restrict__ actb, const u16* __restrict__ wg,
    const float* __restrict__ pre0, const float* __restrict__ cinit,
    u16* __restrict__ hbf, unsigned* __restrict__ gfl,
    float* __restrict__ out) {
  extern __shared__ char smem[];
  u16* wlds = (u16*)smem;                 // 98304 B: W fragments (persistent)
  float* gl = (float*)(smem + 98304);     // 64 x 33 fp32 gate tile

  const int tid = threadIdx.x;
  const int bk = blockIdx.x;
  const int w = tid >> 6;
  const int lane = tid & 63;
  const int q = lane >> 4, r = lane & 15;
  const int n0 = bk * HC;

  {
    const s16x8* src = (const s16x8*)wg + (size_t)bk * 6144;
    s16x8* dst = (s16x8*)wlds;
    for (int i = tid; i < 6144; i += 256) dst[i] = src[i];
  }

  // pointwise ownership: tid<128 -> (row=tid>>1, 4 adjacent cols)
  const int prow = tid >> 1, pcg = (tid & 1) * 4;
  float pr4[16], cr[4];
  if (tid < 128) {
#pragma unroll
    for (int g = 0; g < 4; ++g)
#pragma unroll
      for (int e = 0; e < 4; ++e)
        pr4[g * 4 + e] = pre0[bk * 2048 + prow * 32 + g * 8 + pcg + e];
#pragma unroll
    for (int e = 0; e < 4; ++e) cr[e] = cinit[prow * H + n0 + pcg + e];
  }

  // this wave's producer flag (lanes 0-31 each own one)
  const unsigned* myflag = gfl + w * 32 + (lane & 31);

  __syncthreads();

  for (int t = 0; t < LSTEPS; ++t) {
    const int par = (t - 1) & 1;               // parity of h(t-1) buffer

    // phase 1: zero gate tile; barrier orders it before any phase-5 atomics
#pragma unroll
    for (int j = 0; j < 8; ++j) {
      int i = j * 256 + tid;
      gl[(i >> 5) * GSTR + (i & 31)] = 0.f;
    }
    __syncthreads();

    f32x4 acc[4][2];
#pragma unroll
    for (int mt = 0; mt < 4; ++mt) {
      f32x4 z = {0.f, 0.f, 0.f, 0.f};
      acc[mt][0] = z; acc[mt][1] = z;
    }

    // phase 2: act-part MFMAs (blocked actb, full-line coalesced) — this is
    // the producer-straggler overlap window
    const u16* atb = actb + (size_t)t * 32768;
#pragma unroll
    for (int kk = 0; kk < 4; ++kk) {
      const int kt = w * 4 + kk;
      const s16x8* wb = (const s16x8*)wlds + kt * 128;
      s16x8 bf0 = wb[lane];
      s16x8 bf1 = wb[64 + lane];
#pragma unroll
      for (int mt = 0; mt < 4; ++mt) {
        const int m = mt * 16 + r;
        s16x8 af = *(const s16x8*)(atb + kt * 2048 + q * 512 + m * 8);
        acc[mt][0] = __builtin_amdgcn_mfma_f32_16x16x32_bf16(af, bf0, acc[mt][0], 0, 0, 0);
        acc[mt][1] = __builtin_amdgcn_mfma_f32_16x16x32_bf16(af, bf1, acc[mt][1], 0, 0, 0);
      }
    }

    // phase 3: per-wave dataflow wait — lanes 0-31 poll exactly this wave's
    // 32 producers (blocks w*32..w*32+31). No block-wide join, no barrier.
    if (t && lane < 32) {
      unsigned g = 0;
      while (ld4_coh(myflag) < (unsigned)t) {
        if (++g > (1u << 20)) break;   // bounded spin: wrong-answer beats hang
      }
    }

    // phase 4: h-part MFMAs; h(t-1) read directly from blocked hbf with
    // coherent full-line-coalesced loads, register-double-buffered.
    const u16* hp0 = hbf + par * 65536 + (w * 8) * 2048 + q * 512 + r * 8;
    s16x8 ha0, ha1, ha2, ha3, hb0, hb1, hb2, hb3;

#define HLOAD(d0, d1, d2, d3, KK) do {                                          \
      const u16* hp_ = hp0 + (KK) * 2048;                                       \
      asm volatile("global_load_dwordx4 %0, %1, off sc0 sc1" : "=v"(d0)         \
                   : "v"((const void*)(hp_)) : "memory");                       \
      asm volatile("global_load_dwordx4 %0, %1, off sc0 sc1" : "=v"(d1)         \
                   : "v"((const void*)(hp_ + 128)) : "memory");                 \
      asm volatile("global_load_dwordx4 %0, %1, off sc0 sc1" : "=v"(d2)         \
                   : "v"((const void*)(hp_ + 256)) : "memory");                 \
      asm volatile("global_load_dwordx4 %0, %1, off sc0 sc1" : "=v"(d3)         \
                   : "v"((const void*)(hp_ + 384)) : "memory");                 \
    } while (0)

#define KSTEP(c0, c1, c2, c3, n0_, n1_, n2_, n3_, KK) {                         \
      const s16x8* wb_ = (const s16x8*)wlds + (16 + w * 8 + (KK)) * 128;        \
      s16x8 bf0_ = wb_[lane];                                                   \
      s16x8 bf1_ = wb_[64 + lane];                                              \
      if ((KK) < 7) { HLOAD(n0_, n1_, n2_, n3_, (KK) + 1); }                    \
      if ((KK) < 7) asm volatile("s_waitcnt vmcnt(4)" ::: "memory");            \
      else          asm volatile("s_waitcnt vmcnt(0)" ::: "memory");            \
      __builtin_amdgcn_sched_barrier(0);                                        \
      acc[0][0] = __builtin_amdgcn_mfma_f32_16x16x32_bf16(c0, bf0_, acc[0][0], 0, 0, 0); \
      acc[0][1] = __builtin_amdgcn_mfma_f32_16x16x32_bf16(c0, bf1_, acc[0][1], 0, 0, 0); \
      acc[1][0] = __builtin_amdgcn_mfma_f32_16x16x32_bf16(c1, bf0_, acc[1][0], 0, 0, 0); \
      acc[1][1] = __builtin_amdgcn_mfma_f32_16x16x32_bf16(c1, bf1_, acc[1][1], 0, 0, 0); \
      acc[2][0] = __builtin_amdgcn_mfma_f32_16x16x32_bf16(c2, bf0_, acc[2][0], 0, 0, 0); \
      acc[2][1] = __builtin_amdgcn_mfma_f32_16x16x32_bf16(c2, bf1_, acc[2][1], 0, 0, 0); \
      acc[3][0] = __builtin_amdgcn_mfma_f32_16x16x32_bf16(c3, bf0_, acc[3][0], 0, 0, 0); \
      acc[3][1] = __builtin_amdgcn_mfma_f32_16x16x32_bf16(c3, bf1_, acc[3][1], 0, 0, 0); \
    }

    HLOAD(ha0, ha1, ha2, ha3, 0);
    KSTEP(ha0, ha1, ha2, ha3, hb0, hb1, hb2, hb3, 0)
    KSTEP(hb0, hb1, hb2, hb3, ha0, ha1, ha2, ha3, 1)
    KSTEP(ha0, ha1, ha2, ha3, hb0, hb1, hb2, hb3, 2)
    KSTEP(hb0, hb1, hb2, hb3, ha0, ha1, ha2, ha3, 3)
    KSTEP(ha0, ha1, ha2, ha3, hb0, hb1, hb2, hb3, 4)
    KSTEP(hb0, hb1, hb2, hb3, ha0, ha1, ha2, ha3, 5)
    KSTEP(ha0, ha1, ha2, ha3, hb0, hb1, hb2, hb3, 6)
    KSTEP(hb0, hb1, hb2, hb3, ha0, ha1, ha2, ha3, 7)
#undef KSTEP
#undef HLOAD

    // phase 5: cross-wave K reduction into gate tile
#pragma unroll
    for (int mt = 0; mt < 4; ++mt) {
      const int bb2 = mt * 16 + q * 4;
#pragma unroll
      for (int T = 0; T < 2; ++T) {
        const int lc = T * 16 + r;
#pragma unroll
        for (int e = 0; e < 4; ++e)
          atomicAdd(&gl[(bb2 + e) * GSTR + lc], acc[mt][T][e]);
      }
    }
    __syncthreads();   // implicit full join: all waves observed all 128 flags

    // phase 6: pointwise (tid<128) + publication. h-store issued FIRST so the
    // vmcnt(1) drain below waits only for it (in-order retirement).
    if (tid < 128) {
      float hv[4];
#pragma unroll
      for (int e = 0; e < 4; ++e) {
        const int c = pcg + e;
        float ig = sigm(gl[prow * GSTR + c] + pr4[e]);
        float fg = sigm(gl[prow * GSTR + 8 + c] + pr4[4 + e]);
        float gg = tanh_fast(gl[prow * GSTR + 16 + c] + pr4[8 + e]);
        float og = sigm(gl[prow * GSTR + 24 + c] + pr4[12 + e]);
        cr[e] = fg * cr[e] + ig * gg;
        hv[e] = og * tanh_fast(cr[e]);
      }
      if (t < LSTEPS - 1) {
        s16x4 hb; hb[0] = (short)f2bf(hv[0]); hb[1] = (short)f2bf(hv[1]);
        hb[2] = (short)f2bf(hv[2]); hb[3] = (short)f2bf(hv[3]);
        st8_coh(hbf + (t & 1) * 65536 + bk * 512 + prow * 8 + pcg,
                __builtin_bit_cast(u64, hb));
      }
      f32x4 hv4; hv4[0] = hv[0]; hv4[1] = hv[1]; hv4[2] = hv[2]; hv4[3] = hv[3];
      *(f32x4*)(out + (size_t)t * (B * H) + prow * H + n0 + pcg) = hv4;  // plain
      if (t == LSTEPS - 1) {
        float* hn = out + (size_t)LSTEPS * (B * H);
        float* cn = hn + B * H;
        f32x4 cr4; cr4[0] = cr[0]; cr4[1] = cr[1]; cr4[2] = cr[2]; cr4[3] = cr[3];
        *(f32x4*)(hn + prow * H + n0 + pcg) = hv4;
        *(f32x4*)(cn + prow * H + n0 + pcg) = cr4;
      }
    }

    // publish: wait h-store at LLC (out-store may linger: younger, in-order),
    // block-join, store-only flag. Flag store drains during next step.
    if (t < LSTEPS - 1) {
      asm volatile("s_waitcnt vmcnt(1)" ::: "memory");
      __syncthreads();
      if (tid == 0) st4_coh(gfl + bk, (unsigned)(t + 1));
    }
  }
}

extern "C" void kernel_launch(void* const* d_in, const int* in_sizes, int n_in,
                              void* d_out, int out_size, void* d_ws, size_t ws_size,
                              hipStream_t stream) {
  const float* inf = (const float*)d_in[0];
  const float* act = (const float*)d_in[1];
  const float* h0  = (const float*)d_in[2];
  const float* cst = (const float*)d_in[3];
  const float* Wih = (const float*)d_in[4];
  const float* Whh = (const float*)d_in[5];
  const float* bih = (const float*)d_in[6];
  const float* bhh = (const float*)d_in[7];
  float* out = (float*)d_out;

  char* ws = (char*)d_ws;
  u16* actb      = (u16*)ws;                    //  8,388,608 B (blocked [t][ch][m][8])
  u16* wg        = (u16*)(ws + 8388608);        // 12,582,912 B
  float* pre0    = (float*)(ws + 20971520);     //  1,048,576 B
  u16* hbf       = (u16*)(ws + 22020096);       //    262,144 B (2 par x 128 blk x 1KB)
  unsigned* gfl  = (unsigned*)(ws + 24379456);  //        512 B (128 per-block flags)

  hipLaunchKernelGGL(k_setup, dim3(6176), dim3(256), 0, stream,
                     act, actb, Wih, Whh, wg, h0, hbf, gfl,
                     inf, bih, bhh, pre0);

  hipFuncSetAttribute((const void*)k_rnn, hipFuncAttributeMaxDynamicSharedMemorySize, 106752);
  hipLaunchKernelGGL(k_rnn, dim3(NB), dim3(256), 106752, stream,
                     actb, wg, pre0, cst, hbf, gfl, out);
}

// Round 6
// 908.175 us; speedup vs baseline: 2962.5715x; 2.3770x over previous
//
#include <hip/hip_runtime.h>

// LSTM decoder, MI355X. Persistent recurrence, round 11.
// r10 post-mortem: chain-shortening works; remaining big items are (a) the
// depth-1 h-load pipeline exposing ~8x LLC latency serially in phase 4, and
// (b) zero+barrier+LDS-atomic reduction overhead. This round:
//  - depth-8 register pipeline: all 32 h-loads issued immediately after the
//    poll; KSTEP k waits vmcnt(28-4k). Exposed latency ~1x instead of ~8x.
//  - per-wave LDS gate regions (4 x 64x33 f32): plain ds_writes instead of
//    atomicAdd; no zero pass, no phase-1 barrier; pointwise sums 4 regions.
//  - sync fabric unchanged from r10 (per-wave producer polling, store-only
//    sc0sc1 flags, vmcnt(1) publish drain).
// L=128, B=64, IN_F=ACT_F=512, H=1024.

#define LSTEPS 128
#define B 64
#define ACTF 512
#define H 1024
#define NB 128             // persistent blocks, co-resident (1/CU)
#define HC 8               // h-columns per block
#define GSTR 33            // LDS gate region leading-dim pad (f32)

typedef short s16x8 __attribute__((ext_vector_type(8)));   // 8 x bf16
typedef short s16x4 __attribute__((ext_vector_type(4)));   // 4 x bf16
typedef float f32x4 __attribute__((ext_vector_type(4)));
typedef unsigned short u16;
typedef unsigned long long u64;

__device__ __forceinline__ u16 f2bf(float f) {
  return __builtin_bit_cast(u16, (__bf16)f);   // RNE
}
__device__ __forceinline__ float sigm(float x) { return 1.f / (1.f + __expf(-x)); }
__device__ __forceinline__ float tanh_fast(float x) { return 2.f / (1.f + __expf(-2.f * x)) - 1.f; }

// cross-XCD coherent (LLC-level) accessors — hardware-validated in r7.
__device__ __forceinline__ void st8_coh(void* p, u64 v) {
  asm volatile("global_store_dwordx2 %0, %1, off sc0 sc1" :: "v"(p), "v"(v) : "memory");
}
__device__ __forceinline__ void st4_coh(void* p, unsigned v) {
  asm volatile("global_store_dword %0, %1, off sc0 sc1" :: "v"(p), "v"(v) : "memory");
}
__device__ __forceinline__ unsigned ld4_coh(const void* p) {
  unsigned v;
  asm volatile("global_load_dword %0, %1, off sc0 sc1\n\ts_waitcnt vmcnt(0)"
               : "=v"(v) : "v"(p) : "memory");
  return v;
}

// ---- merged setup kernel: role by block range (unchanged from r10) ----
__global__ void k_setup(const float* __restrict__ act, u16* __restrict__ actb,
                        const float* __restrict__ Wih, const float* __restrict__ Whh,
                        u16* __restrict__ wg,
                        const float* __restrict__ h0, u16* __restrict__ hbf,
                        unsigned* __restrict__ gfl,
                        const float* __restrict__ inf, const float* __restrict__ bih,
                        const float* __restrict__ bhh, float* __restrict__ pre0) {
  const int bb = blockIdx.x;
  const int tid = threadIdx.x;
  if (bb < 2048) {                                   // act fp32 -> bf16, BLOCKED layout
    int id = bb * 256 + tid;                         // 8 contiguous src elems
    const float4* s = (const float4*)act + (size_t)id * 2;
    float4 a = s[0], b = s[1];
    s16x8 o;
    o[0] = (short)f2bf(a.x); o[1] = (short)f2bf(a.y); o[2] = (short)f2bf(a.z); o[3] = (short)f2bf(a.w);
    o[4] = (short)f2bf(b.x); o[5] = (short)f2bf(b.y); o[6] = (short)f2bf(b.z); o[7] = (short)f2bf(b.w);
    // src id = t*4096 + m*64 + chunk  (t=step, m=row, chunk=col/8)
    int t = id >> 12, m = (id >> 6) & 63, ch = id & 63;
    ((s16x8*)actb)[t * 4096 + ch * 64 + m] = o;      // [t][chunk][m][8]
  } else if (bb < 5120) {                            // W fragments (B-frag contiguous)
    int idx = (bb - 2048) * 256 + tid;
    int bk = idx / 6144;
    int lin = idx - bk * 6144;
    int kt = lin >> 7, T = (lin >> 6) & 1, lane = lin & 63;
    int q = lane >> 4, r = lane & 15;
    int local = T * 16 + r;
    int j = (local >> 3) * 1024 + bk * 8 + (local & 7);
    int k = kt * 32 + q * 8;
    const float* src = (k < 512) ? (Wih + (size_t)j * 1024 + 512 + k)
                                 : (Whh + (size_t)j * 1024 + (k - 512));
    s16x8 o;
#pragma unroll
    for (int e = 0; e < 8; ++e) o[e] = (short)f2bf(src[e]);
    ((s16x8*)wg)[(size_t)bk * 6144 + lin] = o;
  } else if (bb < 5152) {                            // h0 -> bf16, BLOCKED, parity 1
    int id = (bb - 5120) * 256 + tid;                // 0..8191, 8 elems each
    const float4* s = (const float4*)h0 + (size_t)id * 2;
    float4 a = s[0], b = s[1];
    s16x8 o;
    o[0] = (short)f2bf(a.x); o[1] = (short)f2bf(a.y); o[2] = (short)f2bf(a.z); o[3] = (short)f2bf(a.w);
    o[4] = (short)f2bf(b.x); o[5] = (short)f2bf(b.y); o[6] = (short)f2bf(b.z); o[7] = (short)f2bf(b.w);
    int row = id >> 7, ch = id & 127;
    ((s16x8*)hbf)[8192 + ch * 64 + row] = o;         // hbf[1][ch][row][8]
    if (bb == 5120 && tid < 128) gfl[tid] = 0u;
  } else {                                           // PRE0 = IF@Wih[:,:512]^T + b_ih + b_hh
    int o = (bb - 5152) * 256 + tid;
    int bk = o >> 11;
    int rr = o & 2047;
    int b = rr >> 5;
    int local = rr & 31;
    int j = (local >> 3) * 1024 + bk * 8 + (local & 7);
    const float4* xa = (const float4*)(inf + (size_t)b * 512);
    const float4* wa = (const float4*)(Wih + (size_t)j * 1024);
    float s = 0.f;
#pragma unroll 4
    for (int k = 0; k < 128; ++k) {
      float4 x = xa[k], w = wa[k];
      s += x.x * w.x + x.y * w.y + x.z * w.z + x.w * w.w;
    }
    pre0[o] = s + bih[j] + bhh[j];
  }
}

// ---- persistent recurrent kernel ----
__global__ void __launch_bounds__(256, 1) k_rnn(
    const u16* __restrict__ actb, const u16* __restrict__ wg,
    const float* __restrict__ pre0, const float* __restrict__ cinit,
    u16* __restrict__ hbf, unsigned* __restrict__ gfl,
    float* __restrict__ out) {
  extern __shared__ char smem[];
  u16* wlds = (u16*)smem;                 // 98304 B: W fragments (persistent)
  float* gl = (float*)(smem + 98304);     // 4 x 64 x 33 fp32 per-wave gate regions

  const int tid = threadIdx.x;
  const int bk = blockIdx.x;
  const int w = tid >> 6;
  const int lane = tid & 63;
  const int q = lane >> 4, r = lane & 15;
  const int n0 = bk * HC;

  {
    const s16x8* src = (const s16x8*)wg + (size_t)bk * 6144;
    s16x8* dst = (s16x8*)wlds;
    for (int i = tid; i < 6144; i += 256) dst[i] = src[i];
  }

  // pointwise ownership: tid<128 -> (row=tid>>1, 4 adjacent cols)
  const int prow = tid >> 1, pcg = (tid & 1) * 4;
  float pr4[16], cr[4];
  if (tid < 128) {
#pragma unroll
    for (int g = 0; g < 4; ++g)
#pragma unroll
      for (int e = 0; e < 4; ++e)
        pr4[g * 4 + e] = pre0[bk * 2048 + prow * 32 + g * 8 + pcg + e];
#pragma unroll
    for (int e = 0; e < 4; ++e) cr[e] = cinit[prow * H + n0 + pcg + e];
  }

  // this wave's producer flag (lanes 0-31 each own one)
  const unsigned* myflag = gfl + w * 32 + (lane & 31);
  float* glw = gl + w * (64 * GSTR);     // this wave's private gate region

  __syncthreads();   // compiler drains vmcnt here -> 0 outstanding at t=0

  for (int t = 0; t < LSTEPS; ++t) {
    const int par = (t - 1) & 1;               // parity of h(t-1) buffer

    f32x4 acc[4][2];
#pragma unroll
    for (int mt = 0; mt < 4; ++mt) {
      f32x4 z = {0.f, 0.f, 0.f, 0.f};
      acc[mt][0] = z; acc[mt][1] = z;
    }

    // phase 2: act-part MFMAs (blocked actb, full-line coalesced, plain
    // cached loads; compiler waits all 16 before its MFMAs -> 0 outstanding
    // VMEM at phase-3 entry for t=0)
    const u16* atb = actb + (size_t)t * 32768;
#pragma unroll
    for (int kk = 0; kk < 4; ++kk) {
      const int kt = w * 4 + kk;
      const s16x8* wb = (const s16x8*)wlds + kt * 128;
      s16x8 bf0 = wb[lane];
      s16x8 bf1 = wb[64 + lane];
#pragma unroll
      for (int mt = 0; mt < 4; ++mt) {
        const int m = mt * 16 + r;
        s16x8 af = *(const s16x8*)(atb + kt * 2048 + q * 512 + m * 8);
        acc[mt][0] = __builtin_amdgcn_mfma_f32_16x16x32_bf16(af, bf0, acc[mt][0], 0, 0, 0);
        acc[mt][1] = __builtin_amdgcn_mfma_f32_16x16x32_bf16(af, bf1, acc[mt][1], 0, 0, 0);
      }
    }

    // phase 3: per-wave dataflow wait — lanes 0-31 poll exactly this wave's
    // 32 producers. Poll's vmcnt(0) also drains any straggler stores, so
    // VMEM outstanding == 0 when the h-burst issues (keeps vmcnt math exact).
    if (t && lane < 32) {
      unsigned g = 0;
      while (ld4_coh(myflag) < (unsigned)t) {
        if (++g > (1u << 20)) break;   // bounded spin: wrong-answer beats hang
      }
    }

    // phase 4: h-part MFMAs, DEPTH-8 pipeline: all 32 coherent loads issued
    // up front; KSTEP k waits vmcnt(28-4k). Exposed LLC latency ~1x not ~8x.
    const u16* hp0 = hbf + par * 65536 + (w * 8) * 2048 + q * 512 + r * 8;
    s16x8 h00,h01,h02,h03, h10,h11,h12,h13, h20,h21,h22,h23, h30,h31,h32,h33,
          h40,h41,h42,h43, h50,h51,h52,h53, h60,h61,h62,h63, h70,h71,h72,h73;

#define HGRP(d0, d1, d2, d3, KK) do {                                           \
      const u16* hp_ = hp0 + (KK) * 2048;                                       \
      asm volatile("global_load_dwordx4 %0, %1, off sc0 sc1" : "=v"(d0)         \
                   : "v"((const void*)(hp_)) : "memory");                       \
      asm volatile("global_load_dwordx4 %0, %1, off sc0 sc1" : "=v"(d1)         \
                   : "v"((const void*)(hp_ + 128)) : "memory");                 \
      asm volatile("global_load_dwordx4 %0, %1, off sc0 sc1" : "=v"(d2)         \
                   : "v"((const void*)(hp_ + 256)) : "memory");                 \
      asm volatile("global_load_dwordx4 %0, %1, off sc0 sc1" : "=v"(d3)         \
                   : "v"((const void*)(hp_ + 384)) : "memory");                 \
    } while (0)

    HGRP(h00,h01,h02,h03, 0); HGRP(h10,h11,h12,h13, 1);
    HGRP(h20,h21,h22,h23, 2); HGRP(h30,h31,h32,h33, 3);
    HGRP(h40,h41,h42,h43, 4); HGRP(h50,h51,h52,h53, 5);
    HGRP(h60,h61,h62,h63, 6); HGRP(h70,h71,h72,h73, 7);

#define KSTEP(c0, c1, c2, c3, KK, VC) {                                         \
      const s16x8* wb_ = (const s16x8*)wlds + (16 + w * 8 + (KK)) * 128;        \
      s16x8 bf0_ = wb_[lane];                                                   \
      s16x8 bf1_ = wb_[64 + lane];                                              \
      asm volatile("s_waitcnt vmcnt(" #VC ")" ::: "memory");                    \
      __builtin_amdgcn_sched_barrier(0);                                        \
      acc[0][0] = __builtin_amdgcn_mfma_f32_16x16x32_bf16(c0, bf0_, acc[0][0], 0, 0, 0); \
      acc[0][1] = __builtin_amdgcn_mfma_f32_16x16x32_bf16(c0, bf1_, acc[0][1], 0, 0, 0); \
      acc[1][0] = __builtin_amdgcn_mfma_f32_16x16x32_bf16(c1, bf0_, acc[1][0], 0, 0, 0); \
      acc[1][1] = __builtin_amdgcn_mfma_f32_16x16x32_bf16(c1, bf1_, acc[1][1], 0, 0, 0); \
      acc[2][0] = __builtin_amdgcn_mfma_f32_16x16x32_bf16(c2, bf0_, acc[2][0], 0, 0, 0); \
      acc[2][1] = __builtin_amdgcn_mfma_f32_16x16x32_bf16(c2, bf1_, acc[2][1], 0, 0, 0); \
      acc[3][0] = __builtin_amdgcn_mfma_f32_16x16x32_bf16(c3, bf0_, acc[3][0], 0, 0, 0); \
      acc[3][1] = __builtin_amdgcn_mfma_f32_16x16x32_bf16(c3, bf1_, acc[3][1], 0, 0, 0); \
    }

    KSTEP(h00,h01,h02,h03, 0, 28)
    KSTEP(h10,h11,h12,h13, 1, 24)
    KSTEP(h20,h21,h22,h23, 2, 20)
    KSTEP(h30,h31,h32,h33, 3, 16)
    KSTEP(h40,h41,h42,h43, 4, 12)
    KSTEP(h50,h51,h52,h53, 5, 8)
    KSTEP(h60,h61,h62,h63, 6, 4)
    KSTEP(h70,h71,h72,h73, 7, 0)
#undef KSTEP
#undef HGRP

    // phase 5: per-wave plain-store reduction into private gate region
    // (no zeroing, no atomics, no extra barrier)
#pragma unroll
    for (int mt = 0; mt < 4; ++mt) {
      const int bb2 = mt * 16 + q * 4;
#pragma unroll
      for (int T = 0; T < 2; ++T) {
        const int lc = T * 16 + r;
#pragma unroll
        for (int e = 0; e < 4; ++e)
          glw[(bb2 + e) * GSTR + lc] = acc[mt][T][e];
      }
    }
    __syncthreads();   // all 4 regions written; also implicit full flag join

    // phase 6: pointwise (tid<128) sums the 4 wave regions + publication
    if (tid < 128) {
      float hv[4];
#pragma unroll
      for (int e = 0; e < 4; ++e) {
        const int c = pcg + e;
        float si = 0.f, sf = 0.f, sg = 0.f, so = 0.f;
#pragma unroll
        for (int ww = 0; ww < 4; ++ww) {
          const float* b = gl + ww * (64 * GSTR) + prow * GSTR;
          si += b[c];
          sf += b[8 + c];
          sg += b[16 + c];
          so += b[24 + c];
        }
        float ig = sigm(si + pr4[e]);
        float fg = sigm(sf + pr4[4 + e]);
        float gg = tanh_fast(sg + pr4[8 + e]);
        float og = sigm(so + pr4[12 + e]);
        cr[e] = fg * cr[e] + ig * gg;
        hv[e] = og * tanh_fast(cr[e]);
      }
      if (t < LSTEPS - 1) {
        s16x4 hb; hb[0] = (short)f2bf(hv[0]); hb[1] = (short)f2bf(hv[1]);
        hb[2] = (short)f2bf(hv[2]); hb[3] = (short)f2bf(hv[3]);
        st8_coh(hbf + (t & 1) * 65536 + bk * 512 + prow * 8 + pcg,
                __builtin_bit_cast(u64, hb));
      }
      f32x4 hv4; hv4[0] = hv[0]; hv4[1] = hv[1]; hv4[2] = hv[2]; hv4[3] = hv[3];
      *(f32x4*)(out + (size_t)t * (B * H) + prow * H + n0 + pcg) = hv4;  // plain
      if (t == LSTEPS - 1) {
        float* hn = out + (size_t)LSTEPS * (B * H);
        float* cn = hn + B * H;
        f32x4 cr4; cr4[0] = cr[0]; cr4[1] = cr[1]; cr4[2] = cr[2]; cr4[3] = cr[3];
        *(f32x4*)(hn + prow * H + n0 + pcg) = hv4;
        *(f32x4*)(cn + prow * H + n0 + pcg) = cr4;
      }
    }

    // publish: wait h-store at LLC (out-store may linger: younger, in-order),
    // block-join, store-only flag. Next step's poll drains the remainder.
    if (t < LSTEPS - 1) {
      asm volatile("s_waitcnt vmcnt(1)" ::: "memory");
      __syncthreads();
      if (tid == 0) st4_coh(gfl + bk, (unsigned)(t + 1));
    }
  }
}

extern "C" void kernel_launch(void* const* d_in, const int* in_sizes, int n_in,
                              void* d_out, int out_size, void* d_ws, size_t ws_size,
                              hipStream_t stream) {
  const float* inf = (const float*)d_in[0];
  const float* act = (const float*)d_in[1];
  const float* h0  = (const float*)d_in[2];
  const float* cst = (const float*)d_in[3];
  const float* Wih = (const float*)d_in[4];
  const float* Whh = (const float*)d_in[5];
  const float* bih = (const float*)d_in[6];
  const float* bhh = (const float*)d_in[7];
  float* out = (float*)d_out;

  char* ws = (char*)d_ws;
  u16* actb      = (u16*)ws;                    //  8,388,608 B (blocked [t][ch][m][8])
  u16* wg        = (u16*)(ws + 8388608);        // 12,582,912 B
  float* pre0    = (float*)(ws + 20971520);     //  1,048,576 B
  u16* hbf       = (u16*)(ws + 22020096);       //    262,144 B (2 par x 128 blk x 1KB)
  unsigned* gfl  = (unsigned*)(ws + 24379456);  //        512 B (128 per-block flags)

  hipLaunchKernelGGL(k_setup, dim3(6176), dim3(256), 0, stream,
                     act, actb, Wih, Whh, wg, h0, hbf, gfl,
                     inf, bih, bhh, pre0);

  // LDS: 98304 (W) + 4*64*33*4 (gate regions) = 132096 B
  hipFuncSetAttribute((const void*)k_rnn, hipFuncAttributeMaxDynamicSharedMemorySize, 132096);
  hipLaunchKernelGGL(k_rnn, dim3(NB), dim3(256), 132096, stream,
                     actb, wg, pre0, cst, hbf, gfl, out);
}

// Round 8
// 889.596 us; speedup vs baseline: 3024.4454x; 1.0209x over previous
//
#include <hip/hip_runtime.h>

// LSTM decoder, MI355X. Persistent recurrence, round 13.
// r12 post-mortem: tag-in-data design sound, fp32 burst = 256 asm-live VGPRs
// -> allocator reuse under async asm loads -> corruption/crash. r13 = same
// hop elimination at r11's PROVEN register footprint:
//  - h published as bf16 16B units; step tag = LSB of bf16 element 0 of each
//    unit (slot t&1, tag (t>>1)&1; stale-distinguishable over the 2-slot
//    cycle). Consumers load+verify+retry; NO flags, NO polling, NO producer
//    drain. No cross-block blocking wait exists anywhere (bounded retry).
//  - 16B unit atomicity: phase 6 assembles tagged units in LDS (hloc); wave0
//    stores whole units at next-iter start (2 stores/wave, uniform; acts
//    issued first so act-waits {14,10,6,2} never block on store acks).
//  - burst: 32 x s16x8 (128 VGPRs, = r11), waits {28..0}; own-block units
//    substituted from hloc (dodges own-store visibility race).
//  - GSTR 33->37: phase-5 writes ~2-way, phase-6 reads conflict-free.
// L=128, B=64, IN_F=ACT_F=512, H=1024.

#define LSTEPS 128
#define B 64
#define ACTF 512
#define H 1024
#define NB 128
#define HC 8
#define GSTR 37            // f32 leading dim of per-wave gate regions

typedef short s16x8 __attribute__((ext_vector_type(8)));
typedef short s16x4 __attribute__((ext_vector_type(4)));
typedef float f32x4 __attribute__((ext_vector_type(4)));
typedef unsigned short u16;
typedef unsigned long long u64;

__device__ __forceinline__ u16 f2bf(float f) {
  return __builtin_bit_cast(u16, (__bf16)f);   // RNE
}
__device__ __forceinline__ float sigm(float x) { return 1.f / (1.f + __expf(-x)); }
__device__ __forceinline__ float tanh_fast(float x) { return 2.f / (1.f + __expf(-2.f * x)) - 1.f; }

// ---- merged setup kernel ----
__global__ void k_setup(const float* __restrict__ act, u16* __restrict__ actb,
                        const float* __restrict__ Wih, const float* __restrict__ Whh,
                        u16* __restrict__ wg,
                        const float* __restrict__ h0, u16* __restrict__ hbp,
                        const float* __restrict__ inf, const float* __restrict__ bih,
                        const float* __restrict__ bhh, float* __restrict__ pre0) {
  const int bb = blockIdx.x;
  const int tid = threadIdx.x;
  if (bb < 2048) {                                   // act fp32 -> bf16, blocked [t][ch][m][8]
    int id = bb * 256 + tid;
    const float4* s = (const float4*)act + (size_t)id * 2;
    float4 a = s[0], b = s[1];
    s16x8 o;
    o[0] = (short)f2bf(a.x); o[1] = (short)f2bf(a.y); o[2] = (short)f2bf(a.z); o[3] = (short)f2bf(a.w);
    o[4] = (short)f2bf(b.x); o[5] = (short)f2bf(b.y); o[6] = (short)f2bf(b.z); o[7] = (short)f2bf(b.w);
    int t = id >> 12, m = (id >> 6) & 63, ch = id & 63;
    ((s16x8*)actb)[t * 4096 + ch * 64 + m] = o;
  } else if (bb < 5120) {                            // W fragments (unchanged)
    int idx = (bb - 2048) * 256 + tid;
    int bk = idx / 6144;
    int lin = idx - bk * 6144;
    int kt = lin >> 7, T = (lin >> 6) & 1, lane = lin & 63;
    int q = lane >> 4, r = lane & 15;
    int local = T * 16 + r;
    int j = (local >> 3) * 1024 + bk * 8 + (local & 7);
    int k = kt * 32 + q * 8;
    const float* src = (k < 512) ? (Wih + (size_t)j * 1024 + 512 + k)
                                 : (Whh + (size_t)j * 1024 + (k - 512));
    s16x8 o;
#pragma unroll
    for (int e = 0; e < 8; ++e) o[e] = (short)f2bf(src[e]);
    ((s16x8*)wg)[(size_t)bk * 6144 + lin] = o;
  } else if (bb < 5152) {                            // h0 -> tagged bf16 units, slot 1
    int id = (bb - 5120) * 256 + tid;                // 0..8191 = unit (blk2,row)
    int blk2 = id >> 6, row = id & 63;
    const float* s = h0 + (size_t)row * H + blk2 * 8;
    s16x8 o;
#pragma unroll
    for (int e = 0; e < 8; ++e) o[e] = (short)f2bf(s[e]);
    o[0] = (short)((o[0] & ~1) | 1);                 // tag=1 (expected at t=0)
    ((s16x8*)(hbp + 65536))[blk2 * 64 + row] = o;
  } else if (bb < 5184) {                            // slot 0 stale init (LSB=1)
    int id = (bb - 5152) * 256 + tid;                // 0..8191 units
    s16x8 p;
#pragma unroll
    for (int e = 0; e < 8; ++e) p[e] = 1;
    ((s16x8*)hbp)[id] = p;
  } else {                                           // PRE0
    int o = (bb - 5184) * 256 + tid;
    int bk = o >> 11;
    int rr = o & 2047;
    int b = rr >> 5;
    int local = rr & 31;
    int j = (local >> 3) * 1024 + bk * 8 + (local & 7);
    const float4* xa = (const float4*)(inf + (size_t)b * 512);
    const float4* wa = (const float4*)(Wih + (size_t)j * 1024);
    float s = 0.f;
#pragma unroll 4
    for (int k = 0; k < 128; ++k) {
      float4 x = xa[k], w = wa[k];
      s += x.x * w.x + x.y * w.y + x.z * w.z + x.w * w.w;
    }
    pre0[o] = s + bih[j] + bhh[j];
  }
}

// ---- asm helpers (all loop VMEM is asm so vmcnt counting is exact) ----
#define AISS(dst, ptr) \
  asm volatile("global_load_dwordx4 %0, %1, off" : "=v"(dst) : "v"(ptr) : "memory");
#define HISS(dst, ptr) \
  asm volatile("global_load_dwordx4 %0, %1, off sc0 sc1" : "=v"(dst) : "v"(ptr) : "memory");
#define WAITV(N) { asm volatile("s_waitcnt vmcnt(" #N ")" ::: "memory"); \
                   __builtin_amdgcn_sched_barrier(0); }
#define LGKM0()  { asm volatile("s_waitcnt lgkmcnt(0)" ::: "memory"); }

// ---- persistent recurrent kernel ----
__global__ void __launch_bounds__(256, 1) k_rnn(
    const u16* __restrict__ actb, const u16* __restrict__ wg,
    const float* __restrict__ pre0, const float* __restrict__ cinit,
    u16* __restrict__ hbp, unsigned* __restrict__ dump,
    float* __restrict__ out) {
  extern __shared__ char smem[];
  u16* wlds  = (u16*)smem;                          // 98304 B: W fragments
  float* gl  = (float*)(smem + 98304);              // 37888 B: 4 x 64 x 37 f32
  u16* hloc  = (u16*)(smem + 98304 + 37888);        // 1024 B: own tagged h units

  const int tid = threadIdx.x;
  const int bk = blockIdx.x;
  const int w = tid >> 6;
  const int lane = tid & 63;
  const int q = lane >> 4, r = lane & 15;
  const int n0 = bk * HC;
  const int prow = tid >> 1, pcg = (tid & 1) * 4;

  {
    const s16x8* src = (const s16x8*)wg + (size_t)bk * 6144;
    s16x8* dst = (s16x8*)wlds;
    for (int i = tid; i < 6144; i += 256) dst[i] = src[i];
  }

  float pr4[16], cr[4];
  if (tid < 128) {
#pragma unroll
    for (int g = 0; g < 4; ++g)
#pragma unroll
      for (int e = 0; e < 4; ++e)
        pr4[g * 4 + e] = pre0[bk * 2048 + prow * 32 + g * 8 + pcg + e];
#pragma unroll
    for (int e = 0; e < 4; ++e) cr[e] = cinit[prow * H + n0 + pcg + e];
  }
  if (tid < 64)   // own h0 units (tagged, from slot 1) into hloc
    *(s16x8*)(hloc + tid * 8) = ((const s16x8*)(hbp + 65536))[bk * 64 + tid];

  const bool ownw = (w == (bk >> 5));
  const int kown = (bk >> 2) & 7;
  const int qown = bk & 3;

  asm volatile("s_waitcnt vmcnt(0) lgkmcnt(0)" ::: "memory");
  __builtin_amdgcn_s_barrier();

  f32x4 hv_prev = {0.f, 0.f, 0.f, 0.f};

  for (int t = 0; t < LSTEPS; ++t) {
    // ---- issue acts (ops 1-16, plain cached) ----
    s16x8 af[4][4];
    const u16* ab = actb + (size_t)t * 32768 + (w * 4) * 2048 + q * 512 + r * 8;
#define AISSG(KK) \
    AISS(af[KK][0], ab + (KK) * 2048);       AISS(af[KK][1], ab + (KK) * 2048 + 128); \
    AISS(af[KK][2], ab + (KK) * 2048 + 256); AISS(af[KK][3], ab + (KK) * 2048 + 384);
    AISSG(0) AISSG(1) AISSG(2) AISSG(3)
#undef AISSG

    // ---- publication of h(t-1)/out(t-1): exactly 2 stores per wave ----
    if (t > 0) {
      if (w == 0) {                       // whole tagged 16B unit from hloc
        s16x8 hu0 = *(const s16x8*)(hloc + lane * 8);
        u16* hp = hbp + (size_t)((t - 1) & 1) * 65536 + (size_t)bk * 512 + lane * 8;
        asm volatile("global_store_dwordx4 %0, %1, off sc0 sc1" :: "v"(hp), "v"(hu0) : "memory");
      } else {
        unsigned* dp = dump + (size_t)bk * 64 + lane;
        asm volatile("global_store_dword %0, %1, off" :: "v"(dp), "v"(0u) : "memory");
      }
      if (tid < 128) {
        float* op = out + (size_t)(t - 1) * 65536 + (size_t)prow * H + n0 + pcg;
        asm volatile("global_store_dwordx4 %0, %1, off" :: "v"(op), "v"(hv_prev) : "memory");
      } else {
        unsigned* dp = dump + (size_t)bk * 64 + lane;
        asm volatile("global_store_dword %0, %1, off" :: "v"(dp), "v"(0u) : "memory");
      }
    } else {
      unsigned* dp = dump + (size_t)bk * 64 + lane;
      asm volatile("global_store_dword %0, %1, off" :: "v"(dp), "v"(0u) : "memory");
      asm volatile("global_store_dword %0, %1, off" :: "v"(dp), "v"(0u) : "memory");
    }

    f32x4 acc[4][2];
#pragma unroll
    for (int mt = 0; mt < 4; ++mt) {
      f32x4 z = {0.f, 0.f, 0.f, 0.f};
      acc[mt][0] = z; acc[mt][1] = z;
    }

    // ---- act-GEMM: waits {14,10,6,2} (acts oldest; stores never waited) ----
#define ACTCH(KK, VC) { \
      const s16x8* wb_ = (const s16x8*)wlds + (w * 4 + (KK)) * 128; \
      s16x8 b0_ = wb_[lane]; s16x8 b1_ = wb_[64 + lane]; \
      WAITV(VC) \
      acc[0][0] = __builtin_amdgcn_mfma_f32_16x16x32_bf16(af[KK][0], b0_, acc[0][0], 0, 0, 0); \
      acc[0][1] = __builtin_amdgcn_mfma_f32_16x16x32_bf16(af[KK][0], b1_, acc[0][1], 0, 0, 0); \
      acc[1][0] = __builtin_amdgcn_mfma_f32_16x16x32_bf16(af[KK][1], b0_, acc[1][0], 0, 0, 0); \
      acc[1][1] = __builtin_amdgcn_mfma_f32_16x16x32_bf16(af[KK][1], b1_, acc[1][1], 0, 0, 0); \
      acc[2][0] = __builtin_amdgcn_mfma_f32_16x16x32_bf16(af[KK][2], b0_, acc[2][0], 0, 0, 0); \
      acc[2][1] = __builtin_amdgcn_mfma_f32_16x16x32_bf16(af[KK][2], b1_, acc[2][1], 0, 0, 0); \
      acc[3][0] = __builtin_amdgcn_mfma_f32_16x16x32_bf16(af[KK][3], b0_, acc[3][0], 0, 0, 0); \
      acc[3][1] = __builtin_amdgcn_mfma_f32_16x16x32_bf16(af[KK][3], b1_, acc[3][1], 0, 0, 0); \
    }
    ACTCH(0, 14) ACTCH(1, 10) ACTCH(2, 6) ACTCH(3, 2)
#undef ACTCH

    // ---- h(t-1) burst: 32 tagged bf16 units (128 VGPRs, = r11 footprint) ----
    const int wtag = ((t - 1) >> 1) & 1;
    const u16* hb2 = hbp + (size_t)((t - 1) & 1) * 65536 + ((w * 8) * 4 + q) * 512 + r * 8;
    s16x8 hu[8][4];
#define HISSG(I) \
    HISS(hu[I][0], hb2 + (I) * 2048)       HISS(hu[I][1], hb2 + (I) * 2048 + 128) \
    HISS(hu[I][2], hb2 + (I) * 2048 + 256) HISS(hu[I][3], hb2 + (I) * 2048 + 384)
    HISSG(0) HISSG(1) HISSG(2) HISSG(3) HISSG(4) HISSG(5) HISSG(6) HISSG(7)

#define SUBST(I) \
    if (ownw && (I) == kown && q == qown) { \
      hu[I][0] = *(const s16x8*)(hloc + (r +  0) * 8); \
      hu[I][1] = *(const s16x8*)(hloc + (r + 16) * 8); \
      hu[I][2] = *(const s16x8*)(hloc + (r + 32) * 8); \
      hu[I][3] = *(const s16x8*)(hloc + (r + 48) * 8); \
    }
#define CHECKOK(I, OK) { int bad_ = 0; \
      bad_ |= (hu[I][0][0] ^ wtag); bad_ |= (hu[I][1][0] ^ wtag); \
      bad_ |= (hu[I][2][0] ^ wtag); bad_ |= (hu[I][3][0] ^ wtag); \
      OK = ((bad_ & 1) == 0); }
#define DOMFMA(I) { \
      const s16x8* wb_ = (const s16x8*)wlds + (16 + w * 8 + (I)) * 128; \
      s16x8 b0_ = wb_[lane]; s16x8 b1_ = wb_[64 + lane]; \
      acc[0][0] = __builtin_amdgcn_mfma_f32_16x16x32_bf16(hu[I][0], b0_, acc[0][0], 0, 0, 0); \
      acc[0][1] = __builtin_amdgcn_mfma_f32_16x16x32_bf16(hu[I][0], b1_, acc[0][1], 0, 0, 0); \
      acc[1][0] = __builtin_amdgcn_mfma_f32_16x16x32_bf16(hu[I][1], b0_, acc[1][0], 0, 0, 0); \
      acc[1][1] = __builtin_amdgcn_mfma_f32_16x16x32_bf16(hu[I][1], b1_, acc[1][1], 0, 0, 0); \
      acc[2][0] = __builtin_amdgcn_mfma_f32_16x16x32_bf16(hu[I][2], b0_, acc[2][0], 0, 0, 0); \
      acc[2][1] = __builtin_amdgcn_mfma_f32_16x16x32_bf16(hu[I][2], b1_, acc[2][1], 0, 0, 0); \
      acc[3][0] = __builtin_amdgcn_mfma_f32_16x16x32_bf16(hu[I][3], b0_, acc[3][0], 0, 0, 0); \
      acc[3][1] = __builtin_amdgcn_mfma_f32_16x16x32_bf16(hu[I][3], b1_, acc[3][1], 0, 0, 0); \
    }

    unsigned stale = 0;
#define KSTEP(I, VC) { WAITV(VC) SUBST(I) int ok_; CHECKOK(I, ok_) \
      if (__all(ok_)) { DOMFMA(I) } else stale |= (1u << (I)); }
    KSTEP(0, 28) KSTEP(1, 24) KSTEP(2, 20) KSTEP(3, 16)
    KSTEP(4, 12) KSTEP(5, 8)  KSTEP(6, 4)  KSTEP(7, 0)
#undef KSTEP

    // ---- retry pass: re-fetch stale groups (bounded; no cross-block wait) ----
    unsigned guard = 0;
    while (stale) {
      if (++guard > 256u) break;   // wrong-answer beats hang
      if (stale & 0x01u) { HISSG(0) } if (stale & 0x02u) { HISSG(1) }
      if (stale & 0x04u) { HISSG(2) } if (stale & 0x08u) { HISSG(3) }
      if (stale & 0x10u) { HISSG(4) } if (stale & 0x20u) { HISSG(5) }
      if (stale & 0x40u) { HISSG(6) } if (stale & 0x80u) { HISSG(7) }
      WAITV(0)
#define RETRY(I, M) if (stale & (M)) { SUBST(I) int ok_; CHECKOK(I, ok_) \
        if (__all(ok_)) { DOMFMA(I) stale &= ~(M); } }
      RETRY(0, 0x01u) RETRY(1, 0x02u) RETRY(2, 0x04u) RETRY(3, 0x08u)
      RETRY(4, 0x10u) RETRY(5, 0x20u) RETRY(6, 0x40u) RETRY(7, 0x80u)
#undef RETRY
    }
#undef HISSG
#undef SUBST
#undef CHECKOK
#undef DOMFMA

    // ---- phase 5: per-wave gate regions (GSTR=37) ----
    {
      float* glw = gl + w * (64 * GSTR);
#pragma unroll
      for (int mt = 0; mt < 4; ++mt) {
        const int bb2 = mt * 16 + q * 4;
#pragma unroll
        for (int T = 0; T < 2; ++T) {
          const int lc = T * 16 + r;
#pragma unroll
          for (int e = 0; e < 4; ++e)
            glw[(bb2 + e) * GSTR + lc] = acc[mt][T][e];
        }
      }
    }
    LGKM0()
    __builtin_amdgcn_s_barrier();        // (A) raw: no vmcnt drain

    // ---- phase 6: pointwise; h kept in regs + tagged bf16 unit in hloc ----
    if (tid < 128) {
      const float* base = gl + prow * GSTR + pcg;
      f32x4 s0 = *(const f32x4*)(base);
      f32x4 s1 = *(const f32x4*)(base + 8);
      f32x4 s2 = *(const f32x4*)(base + 16);
      f32x4 s3 = *(const f32x4*)(base + 24);
#pragma unroll
      for (int ww = 1; ww < 4; ++ww) {
        const float* b2 = base + ww * (64 * GSTR);
        s0 += *(const f32x4*)(b2);
        s1 += *(const f32x4*)(b2 + 8);
        s2 += *(const f32x4*)(b2 + 16);
        s3 += *(const f32x4*)(b2 + 24);
      }
      float hv[4];
#pragma unroll
      for (int e = 0; e < 4; ++e) {
        float ig = sigm(s0[e] + pr4[e]);
        float fg = sigm(s1[e] + pr4[4 + e]);
        float gg = tanh_fast(s2[e] + pr4[8 + e]);
        float og = sigm(s3[e] + pr4[12 + e]);
        cr[e] = fg * cr[e] + ig * gg;
        hv[e] = og * tanh_fast(cr[e]);
        hv_prev[e] = hv[e];
      }
      const int ptag = (t >> 1) & 1;
      s16x4 hb;
      hb[0] = (short)f2bf(hv[0]); hb[1] = (short)f2bf(hv[1]);
      hb[2] = (short)f2bf(hv[2]); hb[3] = (short)f2bf(hv[3]);
      if (pcg == 0) hb[0] = (short)((hb[0] & ~1) | ptag);
      *(s16x4*)(hloc + prow * 8 + pcg) = hb;
    }
    LGKM0()
    __builtin_amdgcn_s_barrier();        // (B) raw
  }

  // ---- epilogue: out[127], h_n, c_n ----
  if (tid < 128) {
    *(f32x4*)(out + (size_t)(LSTEPS - 1) * 65536 + (size_t)prow * H + n0 + pcg) = hv_prev;
    float* hn = out + (size_t)LSTEPS * 65536;
    float* cn = hn + 65536;
    *(f32x4*)(hn + (size_t)prow * H + n0 + pcg) = hv_prev;
    f32x4 cr4; cr4[0] = cr[0]; cr4[1] = cr[1]; cr4[2] = cr[2]; cr4[3] = cr[3];
    *(f32x4*)(cn + (size_t)prow * H + n0 + pcg) = cr4;
  }
}

extern "C" void kernel_launch(void* const* d_in, const int* in_sizes, int n_in,
                              void* d_out, int out_size, void* d_ws, size_t ws_size,
                              hipStream_t stream) {
  const float* inf = (const float*)d_in[0];
  const float* act = (const float*)d_in[1];
  const float* h0  = (const float*)d_in[2];
  const float* cst = (const float*)d_in[3];
  const float* Wih = (const float*)d_in[4];
  const float* Whh = (const float*)d_in[5];
  const float* bih = (const float*)d_in[6];
  const float* bhh = (const float*)d_in[7];
  float* out = (float*)d_out;

  char* ws = (char*)d_ws;
  u16* actb      = (u16*)ws;                    //  8,388,608 B
  u16* wg        = (u16*)(ws + 8388608);        // 12,582,912 B
  float* pre0    = (float*)(ws + 20971520);     //  1,048,576 B
  u16* hbp       = (u16*)(ws + 22020096);       //    262,144 B (2 slot x 128 blk x 512B bf16)
  unsigned* dump = (unsigned*)(ws + 23068672);  //     32,768 B (dummy-store sink)

  hipLaunchKernelGGL(k_setup, dim3(6208), dim3(256), 0, stream,
                     act, actb, Wih, Whh, wg, h0, hbp,
                     inf, bih, bhh, pre0);

  // LDS: 98304 (W) + 37888 (gates) + 1024 (hloc) = 137216 B
  hipFuncSetAttribute((const void*)k_rnn, hipFuncAttributeMaxDynamicSharedMemorySize, 137216);
  hipLaunchKernelGGL(k_rnn, dim3(NB), dim3(256), 137216, stream,
                     actb, wg, pre0, cst, hbp, dump, out);
}